// Round 5
// baseline (363.406 us; speedup 1.0000x reference)
//
#include <hip/hip_runtime.h>
#include <hip/hip_bf16.h>

// AttentionBlock: B=16, N=2048, D=128, fp32 in/out.
// R5: occupancy attack. prep: W->bf16 once. proj: 512x256, 8 waves/CU.
// attn: 512 blocks x 8 waves, in-block split-K (waves 0-3 keys 0-1023,
// waves 4-7 keys 1024-2047), LDS combine. No-max softmax, l via MFMA-ones,
// q_pad folded into V (all validated in R4, absmax 0.031).

#define NEGBIG -4294967296.0f
#define SCALE  0.08838834764831845f      // 1/sqrt(128)

typedef __bf16 bf16x8 __attribute__((ext_vector_type(8)));
typedef __bf16 bf16x4 __attribute__((ext_vector_type(4)));
typedef float  f32x4  __attribute__((ext_vector_type(4)));

// ---------------- Kernel 0: W -> bf16 ----------------
__global__ __launch_bounds__(256) void prep_kernel(
    const float* __restrict__ Wq, const float* __restrict__ Wk,
    const float* __restrict__ Wv, __bf16* __restrict__ wb)
{
    int i = blockIdx.x * 256 + threadIdx.x;          // 12288 float4s
    const float* src = (i < 4096) ? Wq : (i < 8192) ? Wk : Wv;
    int off = (i & 4095) * 4;
    float4 v = *(const float4*)&src[off];
    bf16x4 t = {(__bf16)v.x, (__bf16)v.y, (__bf16)v.z, (__bf16)v.w};
    *(bf16x4*)&wb[(size_t)(i >> 12) * 16384 + off] = t;
}

// ---------------- Kernel 1: projections + masks ----------------
// 512 blocks x 256 thr (4 waves x 16 rows = 64 rows/block).
static __device__ __forceinline__ void do_gemm(
    const __bf16* __restrict__ wb, const float* __restrict__ bias,
    const bf16x8 a[4], __bf16* __restrict__ dst, __bf16* stage,
    const float qpadr[4], bool tp,
    int tid, int wave, int col, int quad, int rowbase)
{
    f32x4 acc[8];
    #pragma unroll
    for (int ct = 0; ct < 8; ++ct) { f32x4 z = {0.f, 0.f, 0.f, 0.f}; acc[ct] = z; }
    #pragma unroll
    for (int f = 0; f < 4; ++f) {
        #pragma unroll
        for (int ct = 0; ct < 8; ++ct) {
            bf16x8 bfr = *(const bf16x8*)&wb[(size_t)(ct * 16 + col) * 128 + f * 32 + quad * 8];
            acc[ct] = __builtin_amdgcn_mfma_f32_16x16x32_bf16(a[f], bfr, acc[ct], 0, 0, 0);
        }
    }
    // C-layout: out-row = quad*4+r, out-d = ct*16+col
    #pragma unroll
    for (int ct = 0; ct < 8; ++ct) {
        float bv = bias[ct * 16 + col];
        #pragma unroll
        for (int r = 0; r < 4; ++r) {
            float v = (acc[ct][r] + bv) * qpadr[r];
            int rr = wave * 16 + quad * 4 + r;
            if (tp) stage[(ct * 16 + col) * 72 + rr] = (__bf16)v;   // [d][m_local]
            else    stage[rr * 136 + ct * 16 + col] = (__bf16)v;    // [row][d]
        }
    }
    __syncthreads();
    if (!tp) {
        // 64 rows x 256 B: 4 thr/row x 64 B
        int r = tid >> 2, seg = (tid & 3) * 32;
        uint4* g4 = (uint4*)(dst + (size_t)(rowbase + r) * 128 + seg);
        const uint4* s4 = (const uint4*)&stage[r * 136 + seg];
        g4[0] = s4[0]; g4[1] = s4[1]; g4[2] = s4[2]; g4[3] = s4[3];
    } else {
        // evT [b][d][2048]; block owns 64-wide m-slice: 128 d-rows x 2 thr x 64 B
        int d = tid >> 1, seg = (tid & 1) * 32;
        int bb = rowbase >> 11, mb = rowbase & 2047;
        uint4* g4 = (uint4*)(dst + (size_t)bb * 128 * 2048 + (size_t)d * 2048 + mb + seg);
        const uint4* s4 = (const uint4*)&stage[d * 72 + seg];
        g4[0] = s4[0]; g4[1] = s4[1]; g4[2] = s4[2]; g4[3] = s4[3];
    }
    __syncthreads();
}

__global__ __launch_bounds__(256) void proj_kernel(
    const float* __restrict__ Q, const float* __restrict__ K,
    const int* __restrict__ PM, const __bf16* __restrict__ wb,
    const float* __restrict__ Bq, const float* __restrict__ Bk,
    const float* __restrict__ Bv,
    __bf16* __restrict__ eqb, __bf16* __restrict__ ekb, __bf16* __restrict__ evT,
    float2* __restrict__ mscale)
{
    __shared__ __bf16 stage[128 * 72];   // 18.4 KB; also covers 64*136=8704
    const int tid  = threadIdx.x;
    const int wave = tid >> 6, lane = tid & 63;
    const int col  = lane & 15, quad = lane >> 4;
    const int rowbase = blockIdx.x * 64;
    const int myrow   = rowbase + wave * 16 + col;

    bf16x8 aq[4], ak[4];
    float qs = 0.f, kss = 0.f;
    #pragma unroll
    for (int f = 0; f < 4; ++f) {
        const float* pq = Q + (size_t)myrow * 128 + f * 32 + quad * 8;
        const float* pk = K + (size_t)myrow * 128 + f * 32 + quad * 8;
        float4 q0 = *(const float4*)pq, q1 = *(const float4*)(pq + 4);
        float4 k0 = *(const float4*)pk, k1 = *(const float4*)(pk + 4);
        float qv[8] = {q0.x, q0.y, q0.z, q0.w, q1.x, q1.y, q1.z, q1.w};
        float kv[8] = {k0.x, k0.y, k0.z, k0.w, k1.x, k1.y, k1.z, k1.w};
        #pragma unroll
        for (int j = 0; j < 8; ++j) {
            qs += qv[j]; kss += kv[j];
            aq[f][j] = (__bf16)qv[j];
            ak[f][j] = (__bf16)kv[j];
        }
    }
    qs  += __shfl_xor(qs, 16);  qs  += __shfl_xor(qs, 32);
    kss += __shfl_xor(kss, 16); kss += __shfl_xor(kss, 32);
    float qpadv = (qs != 0.f) ? 1.f : 0.f;
    if (quad == 0) {
        int pmv = PM[myrow];
        float2 msc;
        msc.x = (pmv != 0) ? SCALE : 0.f;
        msc.y = (pmv != 0) ? 0.f : ((kss == 0.f) ? NEGBIG : 0.f);
        mscale[myrow] = msc;
    }

    const float one4[4] = {1.f, 1.f, 1.f, 1.f};
    float qpr[4];
    #pragma unroll
    for (int r = 0; r < 4; ++r) qpr[r] = __shfl(qpadv, quad * 4 + r);

    do_gemm(wb,           Bq, aq, eqb, stage, one4, false, tid, wave, col, quad, rowbase);
    do_gemm(wb + 16384,   Bk, ak, ekb, stage, one4, false, tid, wave, col, quad, rowbase);
    do_gemm(wb + 32768,   Bv, ak, evT, stage, qpr,  true,  tid, wave, col, quad, rowbase);
}

// ---------------- Kernel 2: split-K flash attention ----------------
// 512 blocks x 512 thr (8 waves). Wave (half, rg): half = wave>>2 selects
// key range [half*1024, +1024); rg = wave&3 selects 16 q-rows. LDS combine
// of the two halves at the end. Barrier-free k-loop (K/V frags from L1/L2).
union AttnSmem {
    __bf16 pt[8][16 * 72];                       // per-wave P strip (18.4 KB)
    struct { float obuf[4][16 * 132]; float lbuf[4][16]; } fin;  // (34 KB)
};

__global__ __launch_bounds__(512) void attn_kernel(
    const __bf16* __restrict__ eqb, const __bf16* __restrict__ ekb,
    const __bf16* __restrict__ evT, const float2* __restrict__ mscale,
    const float* __restrict__ Q, float* __restrict__ out)
{
    __shared__ AttnSmem sm;

    const int tid  = threadIdx.x;
    const int wave = tid >> 6, lane = tid & 63;
    const int col  = lane & 15, quad = lane >> 4;
    const int half = wave >> 2, rg = wave & 3;
    // XCD swizzle: XCD k (= blockIdx%8) hosts batches {2k, 2k+1} only
    const int i  = blockIdx.x;
    const int b  = 2 * (i & 7) + ((i >> 3) & 1);
    const int qt = i >> 4;                        // 0..31 (64-row q-tiles)
    const int rowg0 = b * 2048 + qt * 64 + rg * 16;
    const size_t bV = (size_t)b * 128 * 2048;
    const __bf16* ekbase = ekb + (size_t)b * 2048 * 128;

    bf16x8 aqf[4];
    #pragma unroll
    for (int f = 0; f < 4; ++f)
        aqf[f] = *(const bf16x8*)&eqb[(size_t)(rowg0 + col) * 128 + f * 32 + quad * 8];

    bf16x8 ones;
    #pragma unroll
    for (int j = 0; j < 8; ++j) ones[j] = (__bf16)1.0f;

    f32x4 o[8], lac;
    #pragma unroll
    for (int dt = 0; dt < 8; ++dt) { f32x4 z = {0.f, 0.f, 0.f, 0.f}; o[dt] = z; }
    { f32x4 z = {0.f, 0.f, 0.f, 0.f}; lac = z; }

    for (int it = half * 16; it < half * 16 + 16; ++it) {
        const int mbase = it * 64;
        // S = eq @ ek^T
        f32x4 s[4];
        #pragma unroll
        for (int mt = 0; mt < 4; ++mt) { f32x4 z = {0.f, 0.f, 0.f, 0.f}; s[mt] = z; }
        #pragma unroll
        for (int f = 0; f < 4; ++f) {
            bf16x8 bk[4];
            #pragma unroll
            for (int mt = 0; mt < 4; ++mt)
                bk[mt] = *(const bf16x8*)&ekbase[(size_t)(mbase + mt * 16 + col) * 128 + f * 32 + quad * 8];
            #pragma unroll
            for (int mt = 0; mt < 4; ++mt)
                s[mt] = __builtin_amdgcn_mfma_f32_16x16x32_bf16(aqf[f], bk[mt], s[mt], 0, 0, 0);
        }
        // e = exp(s*msel + movr) -> P strip (A-operand order)
        #pragma unroll
        for (int mt = 0; mt < 4; ++mt) {
            float2 ms = mscale[b * 2048 + mbase + mt * 16 + col];
            #pragma unroll
            for (int r = 0; r < 4; ++r) {
                float e = __expf(s[mt][r] * ms.x + ms.y);
                sm.pt[wave][(quad * 4 + r) * 72 + mt * 16 + col] = (__bf16)e;
            }
        }
        // O += P @ evq ; l += P @ 1
        #pragma unroll
        for (int k2 = 0; k2 < 2; ++k2) {
            bf16x8 pa = *(const bf16x8*)&sm.pt[wave][col * 72 + k2 * 32 + quad * 8];
            #pragma unroll
            for (int dt = 0; dt < 8; ++dt) {
                bf16x8 bv = *(const bf16x8*)&evT[bV + (size_t)(dt * 16 + col) * 2048 + mbase + k2 * 32 + quad * 8];
                o[dt] = __builtin_amdgcn_mfma_f32_16x16x32_bf16(pa, bv, o[dt], 0, 0, 0);
            }
            lac = __builtin_amdgcn_mfma_f32_16x16x32_bf16(pa, ones, lac, 0, 0, 0);
        }
    }

    // ---- combine the two k-halves through LDS ----
    __syncthreads();                       // pt dead everywhere before overlay
    if (half == 1) {
        #pragma unroll
        for (int dt = 0; dt < 8; ++dt)
            #pragma unroll
            for (int r = 0; r < 4; ++r)
                sm.fin.obuf[rg][(quad * 4 + r) * 132 + dt * 16 + col] = o[dt][r];
        if (col == 0) {
            #pragma unroll
            for (int r = 0; r < 4; ++r)
                sm.fin.lbuf[rg][quad * 4 + r] = lac[r];
        }
    }
    __syncthreads();
    if (half == 0) {
        float inv[4];
        #pragma unroll
        for (int r = 0; r < 4; ++r)
            inv[r] = 1.f / (lac[r] + sm.fin.lbuf[rg][quad * 4 + r]);
        #pragma unroll
        for (int dt = 0; dt < 8; ++dt)
            #pragma unroll
            for (int r = 0; r < 4; ++r) {
                float op = o[dt][r] + sm.fin.obuf[rg][(quad * 4 + r) * 132 + dt * 16 + col];
                size_t idx = (size_t)(rowg0 + quad * 4 + r) * 128 + dt * 16 + col;
                out[idx] = op * inv[r] + Q[idx];
            }
    }
}

extern "C" void kernel_launch(void* const* d_in, const int* in_sizes, int n_in,
                              void* d_out, int out_size, void* d_ws, size_t ws_size,
                              hipStream_t stream)
{
    const float* Q  = (const float*)d_in[0];
    const float* K  = (const float*)d_in[1];
    const int*   PM = (const int*)d_in[2];
    const float* Wq = (const float*)d_in[3];
    const float* Bq = (const float*)d_in[4];
    const float* Wk = (const float*)d_in[5];
    const float* Bk = (const float*)d_in[6];
    const float* Wv = (const float*)d_in[7];
    const float* Bv = (const float*)d_in[8];
    float* out = (float*)d_out;

    const size_t SZE = (size_t)16 * 2048 * 128;
    __bf16* eqb = (__bf16*)d_ws;                    // 8 MB
    __bf16* ekb = eqb + SZE;                        // 8 MB
    __bf16* evT = ekb + SZE;                        // 8 MB, [B][D][N], q_pad folded
    float2* mscale = (float2*)(evT + SZE);          // 256 KB
    __bf16* wb = (__bf16*)(mscale + 16 * 2048);     // 96 KB: Wq,Wk,Wv bf16

    prep_kernel<<<48, 256, 0, stream>>>(Wq, Wk, Wv, wb);
    proj_kernel<<<512, 256, 0, stream>>>(Q, K, PM, wb, Bq, Bk, Bv,
                                         eqb, ekb, evT, mscale);
    attn_kernel<<<512, 512, 0, stream>>>(eqb, ekb, evT, mscale, Q, out);
}

// Round 6
// 238.267 us; speedup vs baseline: 1.5252x; 1.5252x over previous
//
#include <hip/hip_runtime.h>
#include <hip/hip_bf16.h>

// AttentionBlock: B=16, N=2048, D=128, fp32 in/out.
// R6 attn: LDS-staged K/V + in-block split-K + 2 blocks/CU.
//   512 blocks x 256 thr; block = 64 q-rows; waves 0-1 = 32-row groups on
//   keys [0,1024), waves 2-3 same rows on [1024,2048); k-tile 32 per half,
//   both halves staged coalesced to LDS; LDS combine at end.
// No-max softmax, l via MFMA-ones, q_pad folded into V (validated R4/R5).

#define NEGBIG -4294967296.0f
#define SCALE  0.08838834764831845f      // 1/sqrt(128)

typedef __bf16 bf16x8 __attribute__((ext_vector_type(8)));
typedef __bf16 bf16x4 __attribute__((ext_vector_type(4)));
typedef float  f32x4  __attribute__((ext_vector_type(4)));

// ---------------- Kernel 0: W -> bf16 ----------------
__global__ __launch_bounds__(256) void prep_kernel(
    const float* __restrict__ Wq, const float* __restrict__ Wk,
    const float* __restrict__ Wv, __bf16* __restrict__ wb)
{
    int i = blockIdx.x * 256 + threadIdx.x;          // 12288 float4s
    const float* src = (i < 4096) ? Wq : (i < 8192) ? Wk : Wv;
    int off = (i & 4095) * 4;
    float4 v = *(const float4*)&src[off];
    bf16x4 t = {(__bf16)v.x, (__bf16)v.y, (__bf16)v.z, (__bf16)v.w};
    *(bf16x4*)&wb[(size_t)(i >> 12) * 16384 + off] = t;
}

// ---------------- Kernel 1: projections + masks ----------------
// 512 blocks x 256 thr (4 waves x 16 rows = 64 rows/block).
static __device__ __forceinline__ void do_gemm(
    const __bf16* __restrict__ wb, const float* __restrict__ bias,
    const bf16x8 a[4], __bf16* __restrict__ dst, __bf16* stage,
    const float qpadr[4], bool tp,
    int tid, int wave, int col, int quad, int rowbase)
{
    f32x4 acc[8];
    #pragma unroll
    for (int ct = 0; ct < 8; ++ct) { f32x4 z = {0.f, 0.f, 0.f, 0.f}; acc[ct] = z; }
    #pragma unroll
    for (int f = 0; f < 4; ++f) {
        #pragma unroll
        for (int ct = 0; ct < 8; ++ct) {
            bf16x8 bfr = *(const bf16x8*)&wb[(size_t)(ct * 16 + col) * 128 + f * 32 + quad * 8];
            acc[ct] = __builtin_amdgcn_mfma_f32_16x16x32_bf16(a[f], bfr, acc[ct], 0, 0, 0);
        }
    }
    #pragma unroll
    for (int ct = 0; ct < 8; ++ct) {
        float bv = bias[ct * 16 + col];
        #pragma unroll
        for (int r = 0; r < 4; ++r) {
            float v = (acc[ct][r] + bv) * qpadr[r];
            int rr = wave * 16 + quad * 4 + r;
            if (tp) stage[(ct * 16 + col) * 72 + rr] = (__bf16)v;   // [d][m_local]
            else    stage[rr * 136 + ct * 16 + col] = (__bf16)v;    // [row][d]
        }
    }
    __syncthreads();
    if (!tp) {
        int r = tid >> 2, seg = (tid & 3) * 32;
        uint4* g4 = (uint4*)(dst + (size_t)(rowbase + r) * 128 + seg);
        const uint4* s4 = (const uint4*)&stage[r * 136 + seg];
        g4[0] = s4[0]; g4[1] = s4[1]; g4[2] = s4[2]; g4[3] = s4[3];
    } else {
        int d = tid >> 1, seg = (tid & 1) * 32;
        int bb = rowbase >> 11, mb = rowbase & 2047;
        uint4* g4 = (uint4*)(dst + (size_t)bb * 128 * 2048 + (size_t)d * 2048 + mb + seg);
        const uint4* s4 = (const uint4*)&stage[d * 72 + seg];
        g4[0] = s4[0]; g4[1] = s4[1]; g4[2] = s4[2]; g4[3] = s4[3];
    }
    __syncthreads();
}

__global__ __launch_bounds__(256) void proj_kernel(
    const float* __restrict__ Q, const float* __restrict__ K,
    const int* __restrict__ PM, const __bf16* __restrict__ wb,
    const float* __restrict__ Bq, const float* __restrict__ Bk,
    const float* __restrict__ Bv,
    __bf16* __restrict__ eqb, __bf16* __restrict__ ekb, __bf16* __restrict__ evT,
    float2* __restrict__ mscale)
{
    __shared__ __bf16 stage[128 * 72];
    const int tid  = threadIdx.x;
    const int wave = tid >> 6, lane = tid & 63;
    const int col  = lane & 15, quad = lane >> 4;
    const int rowbase = blockIdx.x * 64;
    const int myrow   = rowbase + wave * 16 + col;

    bf16x8 aq[4], ak[4];
    float qs = 0.f, kss = 0.f;
    #pragma unroll
    for (int f = 0; f < 4; ++f) {
        const float* pq = Q + (size_t)myrow * 128 + f * 32 + quad * 8;
        const float* pk = K + (size_t)myrow * 128 + f * 32 + quad * 8;
        float4 q0 = *(const float4*)pq, q1 = *(const float4*)(pq + 4);
        float4 k0 = *(const float4*)pk, k1 = *(const float4*)(pk + 4);
        float qv[8] = {q0.x, q0.y, q0.z, q0.w, q1.x, q1.y, q1.z, q1.w};
        float kv[8] = {k0.x, k0.y, k0.z, k0.w, k1.x, k1.y, k1.z, k1.w};
        #pragma unroll
        for (int j = 0; j < 8; ++j) {
            qs += qv[j]; kss += kv[j];
            aq[f][j] = (__bf16)qv[j];
            ak[f][j] = (__bf16)kv[j];
        }
    }
    qs  += __shfl_xor(qs, 16);  qs  += __shfl_xor(qs, 32);
    kss += __shfl_xor(kss, 16); kss += __shfl_xor(kss, 32);
    float qpadv = (qs != 0.f) ? 1.f : 0.f;
    if (quad == 0) {
        int pmv = PM[myrow];
        float2 msc;
        msc.x = (pmv != 0) ? SCALE : 0.f;
        msc.y = (pmv != 0) ? 0.f : ((kss == 0.f) ? NEGBIG : 0.f);
        mscale[myrow] = msc;
    }

    const float one4[4] = {1.f, 1.f, 1.f, 1.f};
    float qpr[4];
    #pragma unroll
    for (int r = 0; r < 4; ++r) qpr[r] = __shfl(qpadv, quad * 4 + r);

    do_gemm(wb,         Bq, aq, eqb, stage, one4, false, tid, wave, col, quad, rowbase);
    do_gemm(wb + 16384, Bk, ak, ekb, stage, one4, false, tid, wave, col, quad, rowbase);
    do_gemm(wb + 32768, Bv, ak, evT, stage, qpr,  true,  tid, wave, col, quad, rowbase);
}

// ---------------- Kernel 2: LDS-staged split-K flash attention ----------------
union AttnSmem {
    struct {
        __bf16 ekt[2][32 * 136];   // [half][m][d]   17.4 KB
        __bf16 evt[2][128 * 40];   // [half][d][m]   20.5 KB
        __bf16 pt[4][32 * 72];     // [wave][q][m]   18.4 KB  (total 56.3 KB)
    } k;
    struct {
        float obuf[2][32 * 132];   // [qwave][q][d]  33.8 KB
        float lbuf[2][32];
    } fin;
};

__global__ __launch_bounds__(256, 2) void attn_kernel(
    const __bf16* __restrict__ eqb, const __bf16* __restrict__ ekb,
    const __bf16* __restrict__ evT, const float2* __restrict__ mscale,
    const float* __restrict__ Q, float* __restrict__ out)
{
    __shared__ AttnSmem sm;

    const int tid  = threadIdx.x;
    const int wave = tid >> 6, lane = tid & 63;
    const int col  = lane & 15, quad = lane >> 4;
    const int qw   = wave & 1;           // q-row group (32 rows)
    const int half = wave >> 1;          // key half: [half*1024, +1024)
    const int i  = blockIdx.x;
    const int b  = 2 * (i & 7) + ((i >> 3) & 1);   // XCD k hosts batches {2k,2k+1}
    const int qt = i >> 4;                          // 0..31, 64-row q-tiles
    const int rowg0 = b * 2048 + qt * 64 + qw * 32;
    const size_t bV = (size_t)b * 128 * 2048;
    const __bf16* ekbase = ekb + (size_t)b * 2048 * 128;

    bf16x8 aqf[2][4];
    #pragma unroll
    for (int q2 = 0; q2 < 2; ++q2)
        #pragma unroll
        for (int f = 0; f < 4; ++f)
            aqf[q2][f] = *(const bf16x8*)&eqb[(size_t)(rowg0 + q2 * 16 + col) * 128 + f * 32 + quad * 8];

    bf16x8 ones;
    #pragma unroll
    for (int j = 0; j < 8; ++j) ones[j] = (__bf16)1.0f;

    f32x4 o[2][8], lac[2];
    #pragma unroll
    for (int q2 = 0; q2 < 2; ++q2) {
        #pragma unroll
        for (int dt = 0; dt < 8; ++dt) { f32x4 z = {0.f, 0.f, 0.f, 0.f}; o[q2][dt] = z; }
        f32x4 z = {0.f, 0.f, 0.f, 0.f}; lac[q2] = z;
    }

    for (int it = 0; it < 32; ++it) {
        // ---- stage both halves' K (2x8KB) and V^T (2x8KB) tiles, coalesced ----
        #pragma unroll
        for (int c = 0; c < 4; ++c) {
            int idx = tid + c * 256;                 // 0..1023
            int h = idx >> 9, r32 = (idx >> 4) & 31, ch = idx & 15;
            *(uint4*)&sm.k.ekt[h][r32 * 136 + ch * 8] =
                *(const uint4*)&ekbase[(size_t)(h * 1024 + it * 32 + r32) * 128 + ch * 8];
        }
        #pragma unroll
        for (int c = 0; c < 4; ++c) {
            int idx = tid + c * 256;
            int h = idx >> 9, d = (idx >> 2) & 127, m8 = (idx & 3) * 8;
            *(uint4*)&sm.k.evt[h][d * 40 + m8] =
                *(const uint4*)&evT[bV + (size_t)d * 2048 + h * 1024 + it * 32 + m8];
        }
        __syncthreads();

        const int mb_h = half * 1024 + it * 32;
        // ---- S = eq @ ek^T (this wave's half, 32 keys) ----
        f32x4 s[2][2];
        #pragma unroll
        for (int q2 = 0; q2 < 2; ++q2)
            #pragma unroll
            for (int mt = 0; mt < 2; ++mt) { f32x4 z = {0.f, 0.f, 0.f, 0.f}; s[q2][mt] = z; }
        #pragma unroll
        for (int f = 0; f < 4; ++f) {
            bf16x8 bk[2];
            #pragma unroll
            for (int mt = 0; mt < 2; ++mt)
                bk[mt] = *(const bf16x8*)&sm.k.ekt[half][(mt * 16 + col) * 136 + f * 32 + quad * 8];
            #pragma unroll
            for (int q2 = 0; q2 < 2; ++q2)
                #pragma unroll
                for (int mt = 0; mt < 2; ++mt)
                    s[q2][mt] = __builtin_amdgcn_mfma_f32_16x16x32_bf16(aqf[q2][f], bk[mt], s[q2][mt], 0, 0, 0);
        }
        // ---- e = exp(s*msel + movr) -> wave-private P strip (A-operand order) ----
        #pragma unroll
        for (int mt = 0; mt < 2; ++mt) {
            float2 ms = mscale[b * 2048 + mb_h + mt * 16 + col];
            #pragma unroll
            for (int q2 = 0; q2 < 2; ++q2)
                #pragma unroll
                for (int r = 0; r < 4; ++r) {
                    float e = __expf(s[q2][mt][r] * ms.x + ms.y);
                    sm.k.pt[wave][(q2 * 16 + quad * 4 + r) * 72 + mt * 16 + col] = (__bf16)e;
                }
        }
        // ---- O += P @ evq ; l += P @ 1   (K=32 consumed by one MFMA) ----
        {
            bf16x8 pa0 = *(const bf16x8*)&sm.k.pt[wave][col * 72 + quad * 8];
            bf16x8 pa1 = *(const bf16x8*)&sm.k.pt[wave][(16 + col) * 72 + quad * 8];
            #pragma unroll
            for (int dt = 0; dt < 8; ++dt) {
                bf16x8 bv = *(const bf16x8*)&sm.k.evt[half][(dt * 16 + col) * 40 + quad * 8];
                o[0][dt] = __builtin_amdgcn_mfma_f32_16x16x32_bf16(pa0, bv, o[0][dt], 0, 0, 0);
                o[1][dt] = __builtin_amdgcn_mfma_f32_16x16x32_bf16(pa1, bv, o[1][dt], 0, 0, 0);
            }
            lac[0] = __builtin_amdgcn_mfma_f32_16x16x32_bf16(pa0, ones, lac[0], 0, 0, 0);
            lac[1] = __builtin_amdgcn_mfma_f32_16x16x32_bf16(pa1, ones, lac[1], 0, 0, 0);
        }
        __syncthreads();
    }

    // ---- combine halves (waves w and w+2 share rows) through LDS overlay ----
    if (half == 1) {
        #pragma unroll
        for (int q2 = 0; q2 < 2; ++q2) {
            #pragma unroll
            for (int dt = 0; dt < 8; ++dt)
                #pragma unroll
                for (int r = 0; r < 4; ++r)
                    sm.fin.obuf[qw][(q2 * 16 + quad * 4 + r) * 132 + dt * 16 + col] = o[q2][dt][r];
            if (col == 0) {
                #pragma unroll
                for (int r = 0; r < 4; ++r)
                    sm.fin.lbuf[qw][q2 * 16 + quad * 4 + r] = lac[q2][r];
            }
        }
    }
    __syncthreads();
    if (half == 0) {
        #pragma unroll
        for (int q2 = 0; q2 < 2; ++q2) {
            float inv[4];
            #pragma unroll
            for (int r = 0; r < 4; ++r)
                inv[r] = 1.f / (lac[q2][r] + sm.fin.lbuf[qw][q2 * 16 + quad * 4 + r]);
            #pragma unroll
            for (int dt = 0; dt < 8; ++dt)
                #pragma unroll
                for (int r = 0; r < 4; ++r) {
                    float op = o[q2][dt][r] + sm.fin.obuf[qw][(q2 * 16 + quad * 4 + r) * 132 + dt * 16 + col];
                    size_t idx = (size_t)(rowg0 + q2 * 16 + quad * 4 + r) * 128 + dt * 16 + col;
                    out[idx] = op * inv[r] + Q[idx];
                }
        }
    }
}

extern "C" void kernel_launch(void* const* d_in, const int* in_sizes, int n_in,
                              void* d_out, int out_size, void* d_ws, size_t ws_size,
                              hipStream_t stream)
{
    const float* Q  = (const float*)d_in[0];
    const float* K  = (const float*)d_in[1];
    const int*   PM = (const int*)d_in[2];
    const float* Wq = (const float*)d_in[3];
    const float* Bq = (const float*)d_in[4];
    const float* Wk = (const float*)d_in[5];
    const float* Bk = (const float*)d_in[6];
    const float* Wv = (const float*)d_in[7];
    const float* Bv = (const float*)d_in[8];
    float* out = (float*)d_out;

    const size_t SZE = (size_t)16 * 2048 * 128;
    __bf16* eqb = (__bf16*)d_ws;                    // 8 MB
    __bf16* ekb = eqb + SZE;                        // 8 MB
    __bf16* evT = ekb + SZE;                        // 8 MB, [B][D][N], q_pad folded
    float2* mscale = (float2*)(evT + SZE);          // 256 KB
    __bf16* wb = (__bf16*)(mscale + 16 * 2048);     // 96 KB: Wq,Wk,Wv bf16

    prep_kernel<<<48, 256, 0, stream>>>(Wq, Wk, Wv, wb);
    proj_kernel<<<512, 256, 0, stream>>>(Q, K, PM, wb, Bq, Bk, Bv,
                                         eqb, ekb, evT, mscale);
    attn_kernel<<<512, 256, 0, stream>>>(eqb, ekb, evT, mscale, Q, out);
}